// Round 5
// baseline (593.665 us; speedup 1.0000x reference)
//
#include <hip/hip_runtime.h>
#include <cstdint>

#define N_NODES 100000
#define N_EDGES 3200000
#define NBUCK   391              // ceil(N_NODES / 256) dst buckets
#define NPAD    (NBUCK * 256)
#define NQUAD   4                // src quadrants (XCD L2 locality)
#define NCELL   (NBUCK * NQUAD)  // 1564 cells
#define QDIV    25000            // src / QDIV -> quadrant
#define K13_BLOCKS 256
#define K13_CHUNK  12500         // 256 * 12500 = 3.2M exactly

// ---- float <-> order-preserving unsigned (signed-float max via uint max) ----
__device__ __forceinline__ unsigned flipf(float f) {
    unsigned u = __float_as_uint(f);
    return (u & 0x80000000u) ? ~u : (u | 0x80000000u);
}
__device__ __forceinline__ float unflipf(unsigned v) {
    unsigned u = (v & 0x80000000u) ? (v & 0x7FFFFFFFu) : ~v;
    return __uint_as_float(u);
}

__device__ __forceinline__ int cell_of(int s, int d) {
    return ((d >> 8) << 2) | (s / QDIV);
}

// ---------------- K1: per-cell edge counts ----------------
__global__ __launch_bounds__(256) void k1_count(const int* __restrict__ ei,
                                                int* __restrict__ total) {
    __shared__ int hist[NCELL];
    for (int t = threadIdx.x; t < NCELL; t += 256) hist[t] = 0;
    __syncthreads();
    int e0 = blockIdx.x * K13_CHUNK;
    for (int k = threadIdx.x; k < K13_CHUNK; k += 256) {
        int e = e0 + k;
        if (e < N_EDGES) atomicAdd(&hist[cell_of(ei[e], ei[N_EDGES + e])], 1);
    }
    __syncthreads();
    for (int t = threadIdx.x; t < NCELL; t += 256) {
        int c = hist[t];
        if (c) atomicAdd(&total[t], c);
    }
}

// ---------------- K2: exclusive scan over NCELL -> cellBase, cursor ----------------
__global__ __launch_bounds__(512) void k2_scan(const int* __restrict__ total,
                                               int* __restrict__ cellBase,
                                               int* __restrict__ cursor) {
    __shared__ int part[512];
    int t = threadIdx.x;
    int base = t * 4;
    int c0 = (base     < NCELL) ? total[base]     : 0;
    int c1 = (base + 1 < NCELL) ? total[base + 1] : 0;
    int c2 = (base + 2 < NCELL) ? total[base + 2] : 0;
    int c3 = (base + 3 < NCELL) ? total[base + 3] : 0;
    int sum = c0 + c1 + c2 + c3;
    part[t] = sum;
    __syncthreads();
    for (int off = 1; off < 512; off <<= 1) {
        int u = (t >= off) ? part[t - off] : 0;
        __syncthreads();
        part[t] += u;
        __syncthreads();
    }
    int ex = part[t] - sum;
    int p0 = ex, p1 = ex + c0, p2 = ex + c0 + c1, p3 = ex + c0 + c1 + c2;
    if (base     < NCELL) { cellBase[base]     = p0; cursor[base]     = p0; }
    if (base + 1 < NCELL) { cellBase[base + 1] = p1; cursor[base + 1] = p1; }
    if (base + 2 < NCELL) { cellBase[base + 2] = p2; cursor[base + 2] = p2; }
    if (base + 3 < NCELL) { cellBase[base + 3] = p3; cursor[base + 3] = p3; }
    if (t == 511) cellBase[NCELL] = part[511];
}

// ---------------- K3: scatter edges into cell-contiguous packed records ----------------
// record: int2 { (src<<8) | (dst&255), bits(norm) }
__global__ __launch_bounds__(256) void k3_scatter(const int* __restrict__ ei,
                                                  const float* __restrict__ norm,
                                                  int* __restrict__ cursor,
                                                  int2* __restrict__ ebuf) {
    __shared__ int hist[NCELL];
    __shared__ int base_l[NCELL];
    __shared__ int run[NCELL];
    for (int t = threadIdx.x; t < NCELL; t += 256) { hist[t] = 0; run[t] = 0; }
    __syncthreads();
    int e0 = blockIdx.x * K13_CHUNK;
    for (int k = threadIdx.x; k < K13_CHUNK; k += 256) {
        int e = e0 + k;
        if (e < N_EDGES) atomicAdd(&hist[cell_of(ei[e], ei[N_EDGES + e])], 1);
    }
    __syncthreads();
    for (int t = threadIdx.x; t < NCELL; t += 256) {
        int c = hist[t];
        base_l[t] = c ? atomicAdd(&cursor[t], c) : 0;
    }
    __syncthreads();
    for (int k = threadIdx.x; k < K13_CHUNK; k += 256) {
        int e = e0 + k;
        if (e < N_EDGES) {
            int s = ei[e];
            int d = ei[N_EDGES + e];
            float w = norm[e];
            int c = cell_of(s, d);
            int r = atomicAdd(&run[c], 1);
            ebuf[base_l[c] + r] = make_int2((s << 8) | (d & 255), __float_as_int(w));
        }
    }
}

// -------- K4a: layer-1 LDS aggregation, 2 blocks/bucket, coalesced-atomic merge --------
__global__ __launch_bounds__(256) void k4a_agg1(
        const float2* __restrict__ x, const int2* __restrict__ ebuf,
        const int* __restrict__ cellBase,
        float* __restrict__ agg1s, unsigned* __restrict__ agg1x) {
    __shared__ float    s_sum[512];
    __shared__ unsigned s_max[512];
    for (int t = threadIdx.x; t < 512; t += 256) { s_sum[t] = 0.0f; s_max[t] = 0u; }
    __syncthreads();

    int b = blockIdx.x >> 1, sp = blockIdx.x & 1;
    int eBeg = cellBase[b * NQUAD], eEnd = cellBase[b * NQUAD + NQUAD];
    int half = (eEnd - eBeg + 1) >> 1;
    int beg = eBeg + sp * half;
    int end = min(eEnd, beg + half);

    int e = beg + threadIdx.x;
    for (; e + 768 < end; e += 1024) {
        int2 r0 = ebuf[e], r1 = ebuf[e + 256], r2 = ebuf[e + 512], r3 = ebuf[e + 768];
        float2 x0 = x[r0.x >> 8], x1 = x[r1.x >> 8], x2 = x[r2.x >> 8], x3 = x[r3.x >> 8];
        float w0 = __int_as_float(r0.y), w1 = __int_as_float(r1.y);
        float w2 = __int_as_float(r2.y), w3 = __int_as_float(r3.y);
        int l0 = (r0.x & 255) * 2, l1 = (r1.x & 255) * 2, l2 = (r2.x & 255) * 2, l3 = (r3.x & 255) * 2;
        atomicAdd(&s_sum[l0],     x0.x * w0); atomicAdd(&s_sum[l0 + 1], x0.y * w0);
        atomicAdd(&s_sum[l1],     x1.x * w1); atomicAdd(&s_sum[l1 + 1], x1.y * w1);
        atomicAdd(&s_sum[l2],     x2.x * w2); atomicAdd(&s_sum[l2 + 1], x2.y * w2);
        atomicAdd(&s_sum[l3],     x3.x * w3); atomicAdd(&s_sum[l3 + 1], x3.y * w3);
        atomicMax(&s_max[l0],     flipf(x0.x)); atomicMax(&s_max[l0 + 1], flipf(x0.y));
        atomicMax(&s_max[l1],     flipf(x1.x)); atomicMax(&s_max[l1 + 1], flipf(x1.y));
        atomicMax(&s_max[l2],     flipf(x2.x)); atomicMax(&s_max[l2 + 1], flipf(x2.y));
        atomicMax(&s_max[l3],     flipf(x3.x)); atomicMax(&s_max[l3 + 1], flipf(x3.y));
    }
    for (; e < end; e += 256) {
        int2 r = ebuf[e];
        float2 xs = x[r.x >> 8];
        float w = __int_as_float(r.y);
        int l = (r.x & 255) * 2;
        atomicAdd(&s_sum[l],     xs.x * w); atomicAdd(&s_sum[l + 1], xs.y * w);
        atomicMax(&s_max[l],     flipf(xs.x)); atomicMax(&s_max[l + 1], flipf(xs.y));
    }
    __syncthreads();

    int base = b * 512;
    for (int u = threadIdx.x; u < 512; u += 256) {
        float v = s_sum[u];
        if (v != 0.0f) atomicAdd(&agg1s[base + u], v);
        unsigned m = s_max[u];
        if (m) atomicMax(&agg1x[base + u], m);
    }
}

// -------- K4b: node1 epilogue -> h1 (fp32), z2 (fp32) --------
__global__ __launch_bounds__(256) void k4b_node1(
        const float2* __restrict__ x,
        const float* __restrict__ agg1s, const unsigned* __restrict__ agg1x,
        const float* __restrict__ w1m_l, const float* __restrict__ b1m,
        const float* __restrict__ w1m_r,
        const float* __restrict__ w1x_l, const float* __restrict__ b1x,
        const float* __restrict__ w1x_r,
        const float* __restrict__ w2m_l,
        float* __restrict__ h1, float* __restrict__ z2) {
    __shared__ float sw[544];
    for (int t = threadIdx.x; t < 544; t += 256) {
        float v;
        if (t < 48)       v = w1m_l[t];
        else if (t < 72)  v = b1m[t - 48];
        else if (t < 120) v = w1m_r[t - 72];
        else if (t < 136) v = w1x_l[t - 120];
        else if (t < 144) v = b1x[t - 136];
        else if (t < 160) v = w1x_r[t - 144];
        else              v = w2m_l[t - 160];
        sw[t] = v;
    }
    __syncthreads();

    int i = blockIdx.x * blockDim.x + threadIdx.x;
    if (i >= N_NODES) return;

    float2 xi = x[i];
    float a0 = agg1s[2 * i], a1 = agg1s[2 * i + 1];
    unsigned m0u = agg1x[2 * i], m1u = agg1x[2 * i + 1];
    float m0 = m0u ? unflipf(m0u) : 0.0f;
    float m1 = m1u ? unflipf(m1u) : 0.0f;

    float hh[32];
#pragma unroll
    for (int k = 0; k < 24; k++) {
        float v = sw[48 + k] + sw[2 * k] * a0 + sw[2 * k + 1] * a1
                + sw[72 + 2 * k] * xi.x + sw[72 + 2 * k + 1] * xi.y;
        hh[k] = fmaxf(v, 0.0f);
    }
#pragma unroll
    for (int k = 0; k < 8; k++) {
        float v = sw[136 + k] + sw[120 + 2 * k] * m0 + sw[120 + 2 * k + 1] * m1
                + sw[144 + 2 * k] * xi.x + sw[144 + 2 * k + 1] * xi.y;
        hh[24 + k] = fmaxf(v, 0.0f);
    }

    float4* h1v = (float4*)(h1 + (size_t)i * 32);
#pragma unroll
    for (int q = 0; q < 8; q++)
        h1v[q] = make_float4(hh[4 * q], hh[4 * q + 1], hh[4 * q + 2], hh[4 * q + 3]);

    // z2 = h1 @ w2m_l^T (fp32)
    float zz[12];
#pragma unroll
    for (int j = 0; j < 12; j++) {
        float v = 0.0f;
#pragma unroll
        for (int k = 0; k < 32; k++) v += hh[k] * sw[160 + j * 32 + k];
        zz[j] = v;
    }
    float4* z2v = (float4*)(z2 + (size_t)i * 12);
    z2v[0] = make_float4(zz[0], zz[1], zz[2], zz[3]);
    z2v[1] = make_float4(zz[4], zz[5], zz[6], zz[7]);
    z2v[2] = make_float4(zz[8], zz[9], zz[10], zz[11]);
}

// -------- K5x: layer-2 MAX aggregation per (bucket, src-quadrant) cell, fp32 h1 gather --------
// blockIdx = b*4+q -> XCD = blockIdx%8 in {q, q+4}: per-XCD h1 slice = 3.2 MB (L2-resident)
__global__ __launch_bounds__(256) void k5x_max(
        const float* __restrict__ h1,
        const int2* __restrict__ ebuf, const int* __restrict__ cellBase,
        unsigned* __restrict__ agg2x) {
    __shared__ unsigned s2x[256 * 32];   // 32 KB, fp32 bit patterns (>=0)
    for (int t = threadIdx.x; t < 256 * 32; t += 256) s2x[t] = 0u;
    __syncthreads();

    int c = blockIdx.x;
    int b = c >> 2;
    int beg = cellBase[c], end = cellBase[c + 1];

    int f  = threadIdx.x & 31;
    int eg = threadIdx.x >> 5;           // 8 edge-groups per block
    int e = beg + eg;
    for (; e + 24 < end; e += 32) {
        int2 r0 = ebuf[e], r1 = ebuf[e + 8], r2 = ebuf[e + 16], r3 = ebuf[e + 24];
        unsigned v0 = __float_as_uint(h1[(size_t)(r0.x >> 8) * 32 + f]);
        unsigned v1 = __float_as_uint(h1[(size_t)(r1.x >> 8) * 32 + f]);
        unsigned v2 = __float_as_uint(h1[(size_t)(r2.x >> 8) * 32 + f]);
        unsigned v3 = __float_as_uint(h1[(size_t)(r3.x >> 8) * 32 + f]);
        atomicMax(&s2x[(r0.x & 255) * 32 + f], v0);
        atomicMax(&s2x[(r1.x & 255) * 32 + f], v1);
        atomicMax(&s2x[(r2.x & 255) * 32 + f], v2);
        atomicMax(&s2x[(r3.x & 255) * 32 + f], v3);
    }
    for (; e < end; e += 8) {
        int2 r = ebuf[e];
        unsigned v = __float_as_uint(h1[(size_t)(r.x >> 8) * 32 + f]);
        atomicMax(&s2x[(r.x & 255) * 32 + f], v);
    }
    __syncthreads();

    int base_x = b * 8192;
    for (int u = threadIdx.x; u < 8192; u += 256) {
        unsigned m = s2x[u];
        if (m) atomicMax(&agg2x[base_x + u], m);
    }
}

// -------- K5s: layer-2 SUM aggregation per cell, fp32 z2 gather, 16 lanes/edge --------
__global__ __launch_bounds__(256) void k5s_sum(
        const float* __restrict__ z2,
        const int2* __restrict__ ebuf, const int* __restrict__ cellBase,
        float* __restrict__ agg2s) {
    __shared__ float s2s[256 * 12];      // 12 KB
    for (int t = threadIdx.x; t < 256 * 12; t += 256) s2s[t] = 0.0f;
    __syncthreads();

    int c = blockIdx.x;
    int b = c >> 2;
    int beg = cellBase[c], end = cellBase[c + 1];

    int f  = threadIdx.x & 15;
    int eg = threadIdx.x >> 4;           // 16 edge-groups per block
    int e = beg + eg;
    for (; e + 48 < end; e += 64) {
        int2 r0 = ebuf[e], r1 = ebuf[e + 16], r2 = ebuf[e + 32], r3 = ebuf[e + 48];
        if (f < 12) {
            float z0 = z2[(size_t)(r0.x >> 8) * 12 + f];
            float z1 = z2[(size_t)(r1.x >> 8) * 12 + f];
            float z2v = z2[(size_t)(r2.x >> 8) * 12 + f];
            float z3 = z2[(size_t)(r3.x >> 8) * 12 + f];
            atomicAdd(&s2s[(r0.x & 255) * 12 + f], z0  * __int_as_float(r0.y));
            atomicAdd(&s2s[(r1.x & 255) * 12 + f], z1  * __int_as_float(r1.y));
            atomicAdd(&s2s[(r2.x & 255) * 12 + f], z2v * __int_as_float(r2.y));
            atomicAdd(&s2s[(r3.x & 255) * 12 + f], z3  * __int_as_float(r3.y));
        }
    }
    for (; e < end; e += 16) {
        int2 r = ebuf[e];
        if (f < 12) {
            float z = z2[(size_t)(r.x >> 8) * 12 + f];
            atomicAdd(&s2s[(r.x & 255) * 12 + f], z * __int_as_float(r.y));
        }
    }
    __syncthreads();

    int base_s = b * 3072;
    for (int u = threadIdx.x; u < 3072; u += 256) {
        float v = s2s[u];
        if (v != 0.0f) atomicAdd(&agg2s[base_s + u], v);
    }
}

// ------------- K6: layer-2 epilogue + MLP head -> out -------------
__global__ __launch_bounds__(256) void k6_node2(
        const float* __restrict__ h1,
        const float* __restrict__ agg2s, const float* __restrict__ agg2x,
        const float* __restrict__ b2m, const float* __restrict__ w2m_r,
        const float* __restrict__ w2x_l, const float* __restrict__ b2x,
        const float* __restrict__ w2x_r,
        const float* __restrict__ w3, const float* __restrict__ b3,
        const float* __restrict__ w4, const float* __restrict__ b4,
        const float* __restrict__ w5, const float* __restrict__ b5,
        float* __restrict__ out) {
    __shared__ float sw[843];
    for (int t = threadIdx.x; t < 843; t += 256) {
        float v;
        if (t < 12)       v = b2m[t];
        else if (t < 396) v = w2m_r[t - 12];
        else if (t < 524) v = w2x_l[t - 396];
        else if (t < 528) v = b2x[t - 524];
        else if (t < 656) v = w2x_r[t - 528];
        else if (t < 784) v = w3[t - 656];
        else if (t < 792) v = b3[t - 784];
        else if (t < 832) v = w4[t - 792];
        else if (t < 837) v = b4[t - 832];
        else if (t < 842) v = w5[t - 837];
        else              v = b5[0];
        sw[t] = v;
    }
    __syncthreads();

    int i = blockIdx.x * blockDim.x + threadIdx.x;
    if (i >= N_NODES) return;

    float hh[32], ax[32];
    const float4* h1v = (const float4*)(h1 + (size_t)i * 32);
    const float4* axv = (const float4*)(agg2x + (size_t)i * 32);
#pragma unroll
    for (int q = 0; q < 8; q++) {
        float4 a = h1v[q];
        hh[4 * q] = a.x; hh[4 * q + 1] = a.y; hh[4 * q + 2] = a.z; hh[4 * q + 3] = a.w;
        float4 bb = axv[q];
        ax[4 * q] = bb.x; ax[4 * q + 1] = bb.y; ax[4 * q + 2] = bb.z; ax[4 * q + 3] = bb.w;
    }

    float h2[16];
#pragma unroll
    for (int j = 0; j < 12; j++) {
        float v = agg2s[(size_t)i * 12 + j] + sw[j];
#pragma unroll
        for (int k = 0; k < 32; k++) v += hh[k] * sw[12 + j * 32 + k];
        h2[j] = fmaxf(v, 0.0f);
    }
#pragma unroll
    for (int j = 0; j < 4; j++) {
        float v = sw[524 + j];
#pragma unroll
        for (int k = 0; k < 32; k++)
            v += ax[k] * sw[396 + j * 32 + k] + hh[k] * sw[528 + j * 32 + k];
        h2[12 + j] = fmaxf(v, 0.0f);
    }

    float t3[8];
#pragma unroll
    for (int j = 0; j < 8; j++) {
        float v = sw[784 + j];
#pragma unroll
        for (int k = 0; k < 16; k++) v += h2[k] * sw[656 + j * 16 + k];
        t3[j] = fmaxf(v, 0.0f);
    }
    float t4[5];
#pragma unroll
    for (int j = 0; j < 5; j++) {
        float v = sw[832 + j];
#pragma unroll
        for (int k = 0; k < 8; k++) v += t3[k] * sw[792 + j * 8 + k];
        t4[j] = fmaxf(v, 0.0f);
    }
    float o = sw[842];
#pragma unroll
    for (int k = 0; k < 5; k++) o += t4[k] * sw[837 + k];
    out[i] = o;
}

extern "C" void kernel_launch(void* const* d_in, const int* in_sizes, int n_in,
                              void* d_out, int out_size, void* d_ws, size_t ws_size,
                              hipStream_t stream) {
    const float* x     = (const float*)d_in[0];
    const int*   ei    = (const int*)d_in[1];
    const float* norm  = (const float*)d_in[2];
    const float* w1m_l = (const float*)d_in[3];
    const float* b1m   = (const float*)d_in[4];
    const float* w1m_r = (const float*)d_in[5];
    const float* w1x_l = (const float*)d_in[6];
    const float* b1x   = (const float*)d_in[7];
    const float* w1x_r = (const float*)d_in[8];
    const float* w2m_l = (const float*)d_in[9];
    const float* b2m   = (const float*)d_in[10];
    const float* w2m_r = (const float*)d_in[11];
    const float* w2x_l = (const float*)d_in[12];
    const float* b2x   = (const float*)d_in[13];
    const float* w2x_r = (const float*)d_in[14];
    const float* w3    = (const float*)d_in[15];
    const float* b3    = (const float*)d_in[16];
    const float* w4    = (const float*)d_in[17];
    const float* b4    = (const float*)d_in[18];
    const float* w5    = (const float*)d_in[19];
    const float* b5    = (const float*)d_in[20];
    float* out = (float*)d_out;

    // workspace layout (~62.5 MB, all fp32)
    char* ws = (char*)d_ws;
    int2*     ebuf = (int2*)ws;                              // 25.6 MB
    float*    h1   = (float*)(ws + (size_t)N_EDGES * 8);     // 32*NPAD = 12.8 MB
    float*    z2   = h1 + (size_t)32 * NPAD;                 // 12*NPAD =  4.8 MB
    float*    aggs = z2 + (size_t)12 * NPAD;                 // 48*NPAD = 19.2 MB zeroed:
    float*    agg1s = aggs;                                  //  2*NPAD
    unsigned* agg1x = (unsigned*)(agg1s + 2 * NPAD);         //  2*NPAD
    float*    agg2s = (float*)(agg1x + 2 * NPAD);            // 12*NPAD
    unsigned* agg2x = (unsigned*)(agg2s + 12 * NPAD);        // 32*NPAD
    int*      total    = (int*)(agg2x + 32 * NPAD);          // NCELL
    int*      cellBase = total + NCELL;                      // NCELL+1
    int*      cursor   = cellBase + NCELL + 1;               // NCELL

    hipMemsetAsync(aggs, 0, (size_t)48 * NPAD * sizeof(float), stream);
    hipMemsetAsync(total, 0, NCELL * sizeof(int), stream);

    k1_count  <<<K13_BLOCKS, 256, 0, stream>>>(ei, total);
    k2_scan   <<<1, 512, 0, stream>>>(total, cellBase, cursor);
    k3_scatter<<<K13_BLOCKS, 256, 0, stream>>>(ei, norm, cursor, ebuf);
    k4a_agg1  <<<NBUCK * 2, 256, 0, stream>>>((const float2*)x, ebuf, cellBase,
                                              agg1s, agg1x);
    k4b_node1 <<<(N_NODES + 255) / 256, 256, 0, stream>>>((const float2*)x, agg1s, agg1x,
                                                          w1m_l, b1m, w1m_r,
                                                          w1x_l, b1x, w1x_r,
                                                          w2m_l, h1, z2);
    k5s_sum   <<<NCELL, 256, 0, stream>>>(z2, ebuf, cellBase, agg2s);
    k5x_max   <<<NCELL, 256, 0, stream>>>(h1, ebuf, cellBase, agg2x);
    k6_node2  <<<(N_NODES + 255) / 256, 256, 0, stream>>>(h1, agg2s, (const float*)agg2x,
                                                          b2m, w2m_r, w2x_l, b2x, w2x_r,
                                                          w3, b3, w4, b4, w5, b5, out);
}